// Round 2
// baseline (8556.427 us; speedup 1.0000x reference)
//
#include <hip/hip_runtime.h>
#include <math.h>

typedef __attribute__((ext_vector_type(8))) short bf16x8;
typedef __attribute__((ext_vector_type(4))) float f32x4;
typedef unsigned int u32;
typedef unsigned short u16;
typedef unsigned long long u64;

#define BB 16
#define LL 512
#define TT 128
#define VV 21128
#define DD 512

__device__ __forceinline__ float b2f(u16 h){ return __uint_as_float(((u32)h) << 16); }
__device__ __forceinline__ u16 f2bf(float x){
    u32 u = __float_as_uint(x);
    return (u16)((u + 0x7fffu + ((u >> 16) & 1u)) >> 16);
}
__device__ __forceinline__ float sigf(float x){ return 1.0f / (1.0f + __expf(-x)); }
__device__ __forceinline__ bf16x8 pack8(float4 a, float4 b){
    bf16x8 r;
    r[0]=(short)f2bf(a.x); r[1]=(short)f2bf(a.y); r[2]=(short)f2bf(a.z); r[3]=(short)f2bf(a.w);
    r[4]=(short)f2bf(b.x); r[5]=(short)f2bf(b.y); r[6]=(short)f2bf(b.z); r[7]=(short)f2bf(b.w);
    return r;
}

// ---------------- init tagged h buffer ----------------
// layout: u32 hbuf[dir][parity][batch=16][dim=512]; word = (bf16 h)<<16 | tag16
// h_k lives at parity k&1 with tag k+1. Init: parity0 = h_0=0 tag1, parity1 = tag0.
__global__ void k_init(u32* hb){
    int i = blockIdx.x * 256 + threadIdx.x;    // 32768
    hb[i] = ((i >> 13) & 1) ? 0u : 1u;
}

// ---------------- embedding: emb2[l*16+b] = bf16(E[doc[b][l]]) ----------------
__global__ void k_embed(const int* __restrict__ doc, const float* __restrict__ E,
                        u16* __restrict__ emb2){
    int r = blockIdx.x;            // l*16 + b
    int lane = threadIdx.x;        // 64
    int l = r >> 4, b = r & 15;
    int tok = doc[b * LL + l];
    const float* src = E + (size_t)tok * DD + lane * 8;
    float4 a = *(const float4*)(src);
    float4 c = *(const float4*)(src + 4);
    *(bf16x8*)(emb2 + (size_t)r * DD + lane * 8) = pack8(a, c);
}

// ---------------- generic 128x128 MFMA GEMM, C = A(bf16) * Bt(f32->bf16)^T ----
// MODE 0: out bf16 = acc + b1[n] + b2[n]     (row-major MxN)
// MODE 1: out bf16 = tanh(acc + b1[n])       (row-major MxN)
// MODE 2: pred epilogue: rows = b*128 + t; out[b,v,t] f32 (B,V,T), t==0 -> 0
template<int MODE>
__global__ __launch_bounds__(256) void k_gemm(
    const u16* __restrict__ A, const float* __restrict__ Bt, void* __restrict__ Out,
    const float* __restrict__ b1, const float* __restrict__ b2, int M, int N, int K)
{
    __shared__ u16 smem[17408];           // 34816 B
    u16* sA = smem;                       // 128 x 56
    u16* sB = smem + 128 * 56;
    int tid = threadIdx.x;
    int nb = blockIdx.x, mb = blockIdx.y;
    int wv = tid >> 6, lane = tid & 63;
    int wm = wv >> 1, wn = wv & 1;
    int lrow = lane & 15, quad = lane >> 4;
    f32x4 acc[4][4] = {};
    int kt_n = K >> 5;
    for (int kt = 0; kt < kt_n; ++kt){
        int k0 = kt << 5;
        bf16x8 va[2];
        u64 qb[4];
        #pragma unroll
        for (int h = 0; h < 2; ++h){
            int c = tid + (h << 8);
            int row = c >> 2, c4 = c & 3;
            va[h] = *(const bf16x8*)(A + (size_t)(mb * 128 + row) * K + k0 + c4 * 8);
        }
        #pragma unroll
        for (int h = 0; h < 4; ++h){
            int c = tid + (h << 8);
            int row = c >> 3, seg = c & 7;
            int rb = nb * 128 + row; rb = rb < N ? rb : N - 1;
            float4 v = *(const float4*)(Bt + (size_t)rb * K + k0 + seg * 4);
            qb[h] = (u64)f2bf(v.x) | ((u64)f2bf(v.y) << 16) |
                    ((u64)f2bf(v.z) << 32) | ((u64)f2bf(v.w) << 48);
        }
        __syncthreads();
        #pragma unroll
        for (int h = 0; h < 2; ++h){
            int c = tid + (h << 8);
            int row = c >> 2, c4 = c & 3;
            *(bf16x8*)(sA + row * 56 + c4 * 8) = va[h];
        }
        #pragma unroll
        for (int h = 0; h < 4; ++h){
            int c = tid + (h << 8);
            int row = c >> 3, seg = c & 7;
            *(u64*)(sB + row * 56 + seg * 4) = qb[h];
        }
        __syncthreads();
        bf16x8 af[4], bfr[4];
        #pragma unroll
        for (int i = 0; i < 4; ++i){
            af[i]  = *(const bf16x8*)(sA + (wm * 64 + i * 16 + lrow) * 56 + quad * 8);
            bfr[i] = *(const bf16x8*)(sB + (wn * 64 + i * 16 + lrow) * 56 + quad * 8);
        }
        #pragma unroll
        for (int i = 0; i < 4; ++i)
            #pragma unroll
            for (int j = 0; j < 4; ++j)
                acc[i][j] = __builtin_amdgcn_mfma_f32_16x16x32_bf16(af[i], bfr[j], acc[i][j], 0, 0, 0);
    }

    if (MODE == 0 || MODE == 1){
        u16* O = (u16*)Out;
        #pragma unroll
        for (int i = 0; i < 4; ++i){
            int rowb = mb * 128 + wm * 64 + i * 16 + quad * 4;
            #pragma unroll
            for (int j = 0; j < 4; ++j){
                int col = nb * 128 + wn * 64 + j * 16 + lrow;
                float bias = b1[col] + (b2 ? b2[col] : 0.0f);
                #pragma unroll
                for (int r = 0; r < 4; ++r){
                    float v = acc[i][j][r] + bias;
                    if (MODE == 1) v = tanhf(v);
                    O[(size_t)(rowb + r) * N + col] = f2bf(v);
                }
            }
        }
    } else {
        // transpose tile through LDS (f32), 2 phases of 64 v-rows
        float* Of = (float*)Out;
        float* lds_f = (float*)smem;          // 64 x 132 f32 = 33792 B
        #pragma unroll
        for (int h = 0; h < 2; ++h){
            __syncthreads();
            if (wn == h){
                #pragma unroll
                for (int j = 0; j < 4; ++j){
                    int nl = j * 16 + lrow;
                    int vg = nb * 128 + h * 64 + nl;
                    float bias = (vg < VV) ? b1[vg] : 0.0f;
                    #pragma unroll
                    for (int i = 0; i < 4; ++i){
                        #pragma unroll
                        for (int r = 0; r < 4; ++r){
                            int tl = wm * 64 + i * 16 + quad * 4 + r;
                            lds_f[nl * 132 + tl] = (tl == 0) ? 0.0f : (acc[i][j][r] + bias);
                        }
                    }
                }
            }
            __syncthreads();
            int vloc = tid >> 2, seg = tid & 3;
            int ng = nb * 128 + h * 64 + vloc;
            if (ng < VV){
                float4* dst = (float4*)(Of + ((size_t)mb * VV + ng) * TT + seg * 32);
                const float4* src = (const float4*)(lds_f + vloc * 132 + seg * 32);
                #pragma unroll
                for (int q = 0; q < 8; ++q) dst[q] = src[q];
            }
        }
    }
}

// ---------------- persistent BiLSTM scan, tag-validated transport ----------------
// 16 blocks x 256 thr. dir = blk>>3; wave slice w = (blk&7)*4 + wv in 0..31,
// dims d0 = w*16. Each wave computes all 4 gates for its 16 dims.
// NO fences, NO flags, NO acquire/release anywhere: each h word carries its
// step tag ((bf16 h)<<16 | (s+2)); consumers poll the data itself with relaxed
// bypass loads and validate tags. Double-buffer by step parity; overrun is
// impossible by transitivity (reaching step s requires having read all of s-1,
// which required every wave to have read all of s-2).
__global__ __launch_bounds__(256, 1) void k_lstm(
    const u16* __restrict__ xg_f, const u16* __restrict__ xg_b,
    const float* __restrict__ Whh_f, const float* __restrict__ Whh_b,
    u16* __restrict__ hist_f, u16* __restrict__ hist_b,
    u32* __restrict__ hbuf)
{
    int tid = threadIdx.x;
    int wv = tid >> 6, lane = tid & 63;
    int blk = blockIdx.x;
    int dir = blk >> 3;
    int w = ((blk & 7) << 2) + wv;        // 0..31
    int d0 = w << 4;
    int lrow = lane & 15, quad = lane >> 4;

    const u16* xg  = dir ? xg_b : xg_f;
    const float* Whh = dir ? Whh_b : Whh_f;
    u16* hist = dir ? hist_b : hist_f;
    u32* hb_base = hbuf + (dir << 14);    // 2 parity buffers x 8192 u32

    // B fragments: Whh rows (gate*512 + d0 + lrow), all K, packed bf16
    bf16x8 bfr[4][16];
    #pragma unroll
    for (int g = 0; g < 4; ++g){
        const float* wp = Whh + (size_t)((g << 9) + d0 + lrow) * DD;
        #pragma unroll
        for (int kb = 0; kb < 16; ++kb){
            float4 x0 = *(const float4*)(wp + kb * 32 + quad * 8);
            float4 x1 = *(const float4*)(wp + kb * 32 + quad * 8 + 4);
            bfr[g][kb] = pack8(x0, x1);
        }
    }
    float c_reg[4] = {0.0f, 0.0f, 0.0f, 0.0f};

    for (int s = 0; s < LL; ++s){
        int t = dir ? (LL - 1 - s) : s;
        u32* hb_r = hb_base + ((s & 1) << 13);
        u32* hb_w = hb_base + (((s + 1) & 1) << 13);
        u32 tagr = (u32)(s + 1);
        u32 tagtag = tagr | (tagr << 16);
        u32 tagw = (u32)(s + 2);

        // prefetch xg (precomputed input gates) — issue before the poll
        u16 xv[4][4];
        const u16* xgp = xg + (size_t)(t << 4) * 2048 + d0 + lrow;
        #pragma unroll
        for (int g = 0; g < 4; ++g)
            #pragma unroll
            for (int r = 0; r < 4; ++r)
                xv[g][r] = xgp[(size_t)((quad << 2) + r) * 2048 + (g << 9)];
        __builtin_amdgcn_sched_barrier(0);

        // poll-load h_s directly; tags validate completeness (no flags)
        // lane(lrow=batch, quad): u64 q -> kb=q>>2, m=q&3 at row + kb*16 + quad*4 + m
        const u64* hrow = (const u64*)hb_r + (lrow << 8) + (quad << 2);
        u64 wd[64];
        while (1){
            #pragma unroll
            for (int q = 0; q < 64; ++q)
                wd[q] = __hip_atomic_load(hrow + ((q >> 2) << 4) + (q & 3),
                                          __ATOMIC_RELAXED, __HIP_MEMORY_SCOPE_AGENT);
            u32 orr = 0;
            #pragma unroll
            for (int q = 0; q < 64; ++q){
                u32 lo = (u32)wd[q], hi = (u32)(wd[q] >> 32);
                orr |= __builtin_amdgcn_perm(hi, lo, 0x05040100u) ^ tagtag;
            }
            if (__all(orr == 0)) break;
            __builtin_amdgcn_s_sleep(1);
        }

        // pack high halves into A fragments + MFMA (4 gates)
        f32x4 acc[4] = {};
        #pragma unroll
        for (int kb = 0; kb < 16; ++kb){
            union { bf16x8 v; u32 u[4]; } af;
            #pragma unroll
            for (int m = 0; m < 4; ++m){
                u64 x = wd[(kb << 2) + m];
                af.u[m] = __builtin_amdgcn_perm((u32)(x >> 32), (u32)x, 0x07060302u);
            }
            #pragma unroll
            for (int g = 0; g < 4; ++g)
                acc[g] = __builtin_amdgcn_mfma_f32_16x16x32_bf16(af.v, bfr[g][kb], acc[g], 0, 0, 0);
        }

        // gates: lane holds (dim = d0+lrow, batches quad*4+r); all 4 gates local
        #pragma unroll
        for (int r = 0; r < 4; ++r){
            float gi = acc[0][r] + b2f(xv[0][r]);
            float gf = acc[1][r] + b2f(xv[1][r]);
            float gg = acc[2][r] + b2f(xv[2][r]);
            float go = acc[3][r] + b2f(xv[3][r]);
            float cv = sigf(gf) * c_reg[r] + sigf(gi) * tanhf(gg);
            c_reg[r] = cv;
            u32 me = (u32)f2bf(sigf(go) * tanhf(cv));
            int batch = (quad << 2) + r;
            // publish h_{s+1}: tag rides with data, fire-and-forget
            __hip_atomic_store(hb_w + (batch << 9) + d0 + lrow, (me << 16) | tagw,
                               __ATOMIC_RELAXED, __HIP_MEMORY_SCOPE_AGENT);
            u32 ot = __shfl_xor(me, 1);
            if (!(lane & 1)){
                *(u32*)(hist + (size_t)((t << 4) + batch) * DD + d0 + lrow) = me | (ot << 16);
            }
        }
    }
}

// ---------------- hidden = tanh([h_f|h_b] @ fc_W^T + fc_b) ----------------
__global__ void k_fc(const u16* __restrict__ hist_f, const u16* __restrict__ hist_b,
                     const float* __restrict__ fcW, const float* __restrict__ fcB,
                     u16* __restrict__ hidden){
    int idx = blockIdx.x * 256 + threadIdx.x;   // 8192
    int b = idx >> 9, n = idx & 511;
    const u16* hf = hist_f + (size_t)(511 * 16 + b) * DD;
    const u16* hb = hist_b + (size_t)b * DD;    // t = 0
    const float* w = fcW + (size_t)n * 1024;
    float sacc = 0.0f;
    for (int k = 0; k < 512; ++k) sacc += b2f(hf[k]) * w[k];
    for (int k = 0; k < 512; ++k) sacc += b2f(hb[k]) * w[512 + k];
    hidden[b * 512 + n] = f2bf(tanhf(sacc + fcB[n]));
}

// ---------------- X_att row = [hidden_b | h_f[b,l] | h_b[b,l]] ----------------
__global__ void k_packatt(const u16* __restrict__ hidden, const u16* __restrict__ hist_f,
                          const u16* __restrict__ hist_b, u16* __restrict__ X){
    int r = blockIdx.x;              // b*512 + l
    int b = r >> 9, l = r & 511;
    u16* xr = X + (size_t)r * 1536;
    const u16* hf = hist_f + (size_t)(l * 16 + b) * DD;
    const u16* hb = hist_b + (size_t)(l * 16 + b) * DD;
    const u16* hd = hidden + b * 512;
    for (int j = threadIdx.x; j < 512; j += 256){
        xr[j] = hd[j];
        xr[512 + j] = hf[j];
        xr[1024 + j] = hb[j];
    }
}

// ---------------- att[b,l] = v_w . energy_row, masked ----------------
__global__ void k_att(const u16* __restrict__ energy, const float* __restrict__ vw,
                      const int* __restrict__ doc, float* __restrict__ att){
    int r = blockIdx.x * 4 + (threadIdx.x >> 6);
    int lane = threadIdx.x & 63;
    bf16x8 e = *(const bf16x8*)(energy + (size_t)r * 512 + lane * 8);
    float4 v0 = *(const float4*)(vw + lane * 8);
    float4 v1 = *(const float4*)(vw + lane * 8 + 4);
    float sacc = b2f((u16)e[0]) * v0.x + b2f((u16)e[1]) * v0.y +
                 b2f((u16)e[2]) * v0.z + b2f((u16)e[3]) * v0.w +
                 b2f((u16)e[4]) * v1.x + b2f((u16)e[5]) * v1.y +
                 b2f((u16)e[6]) * v1.z + b2f((u16)e[7]) * v1.w;
    #pragma unroll
    for (int o = 1; o < 64; o <<= 1) sacc += __shfl_xor(sacc, o);
    if (lane == 0){
        int b = r >> 9, l = r & 511;
        att[r] = (doc[b * 512 + l] != 0) ? sacc : -1e10f;
    }
}

// ---------------- softmax over L + weighted = sum_l a[l]*enc[b,l] ----------------
__global__ __launch_bounds__(256) void k_smw(const float* __restrict__ att,
                                             const u16* __restrict__ hist_f,
                                             const u16* __restrict__ hist_b,
                                             float* __restrict__ weighted){
    __shared__ float sa[512];
    __shared__ float red[256];
    int b = blockIdx.x, tid = threadIdx.x;
    float a0 = att[b * 512 + tid], a1 = att[b * 512 + 256 + tid];
    red[tid] = fmaxf(a0, a1); __syncthreads();
    for (int o = 128; o > 0; o >>= 1){ if (tid < o) red[tid] = fmaxf(red[tid], red[tid + o]); __syncthreads(); }
    float mx = red[0]; __syncthreads();
    float e0 = __expf(a0 - mx), e1 = __expf(a1 - mx);
    red[tid] = e0 + e1; __syncthreads();
    for (int o = 128; o > 0; o >>= 1){ if (tid < o) red[tid] += red[tid + o]; __syncthreads(); }
    float inv = 1.0f / red[0];
    sa[tid] = e0 * inv; sa[256 + tid] = e1 * inv;
    __syncthreads();
    #pragma unroll
    for (int ch = 0; ch < 4; ++ch){
        int e = (ch << 8) + tid;
        const u16* src = (e < 512) ? (hist_f + b * DD + e) : (hist_b + b * DD + (e - 512));
        float acc = 0.0f;
        for (int l = 0; l < 512; ++l) acc += sa[l] * b2f(src[(size_t)l * 16 * DD]);
        weighted[b * 1024 + e] = acc;
    }
}

// ---------------- decoder input packing ----------------
__global__ void k_packdec(const int* __restrict__ sids, const float* __restrict__ E,
                          const float* __restrict__ weighted,
                          u16* __restrict__ X_dec, u16* __restrict__ X_pred){
    int r = blockIdx.x;             // b*128 + t
    int b = r >> 7, t = r & 127;
    u16* xd = X_dec + (size_t)r * 1536;
    u16* xp = X_pred + (size_t)r * 2048;
    const float* er = (t > 0) ? (E + (size_t)sids[b * 128 + t - 1] * DD) : (const float*)0;
    for (int j = threadIdx.x; j < 512; j += 256){
        u16 v = (t > 0) ? f2bf(er[j]) : (u16)0;
        xd[j] = v; xp[1536 + j] = v;
    }
    for (int j = threadIdx.x; j < 1024; j += 256){
        u16 wv = f2bf(weighted[b * 1024 + j]);
        xd[512 + j] = wv; xp[512 + j] = wv;
    }
}

// ---------------- decoder gates (c0=0, f unused) ----------------
__global__ void k_gate(const u16* __restrict__ g, u16* __restrict__ X_pred){
    int idx = blockIdx.x * 256 + threadIdx.x;   // 2048*512
    int r = idx >> 9, d = idx & 511;
    const u16* gr = g + (size_t)r * 2048;
    float gi = b2f(gr[d]), gg = b2f(gr[1024 + d]), go = b2f(gr[1536 + d]);
    float c = sigf(gi) * tanhf(gg);
    X_pred[(size_t)r * 2048 + d] = f2bf(sigf(go) * tanhf(c));
}

// ---------------- loss: online softmax partials over V chunks ----------------
__global__ void k_lossp(const float* __restrict__ out, float* __restrict__ part){
    int b = blockIdx.x >> 5, ch = blockIdx.x & 31;
    int t = threadIdx.x;            // 128
    int v0 = ch * 661, v1 = v0 + 661; if (v1 > VV) v1 = VV;
    const float* col = out + (size_t)b * VV * TT + t;
    float m = -1e30f, sacc = 0.0f;
    for (int v = v0; v < v1; ++v){
        float x = col[(size_t)v * TT];
        float nm = fmaxf(m, x);
        sacc = sacc * __expf(m - nm) + __expf(x - nm);
        m = nm;
    }
    float2* p = (float2*)part;
    p[((b * 32 + ch) << 7) + t] = make_float2(m, sacc);
}

__global__ __launch_bounds__(256) void k_lossm(const float* __restrict__ part,
                                               const float* __restrict__ out,
                                               const int* __restrict__ sids,
                                               float* __restrict__ loss_out){
    __shared__ float red[256];
    int tid = threadIdx.x;
    float local = 0.0f;
    #pragma unroll
    for (int p8 = 0; p8 < 8; ++p8){
        int pair = (p8 << 8) + tid;             // 0..2047
        int b = pair >> 7, t = pair & 127;
        const float2* pp = (const float2*)part + ((size_t)(b * 32) << 7) + t;
        float M = -1e30f;
        for (int c = 0; c < 32; ++c) M = fmaxf(M, pp[c << 7].x);
        float S = 0.0f;
        for (int c = 0; c < 32; ++c){ float2 q = pp[c << 7]; S += q.y * __expf(q.x - M); }
        float logZ = M + __logf(S);
        int tgt = sids[b * 128 + t];
        float x = out[(size_t)b * VV * TT + (size_t)tgt * TT + t];
        local += (logZ - x);
    }
    red[tid] = local; __syncthreads();
    for (int o = 128; o > 0; o >>= 1){ if (tid < o) red[tid] += red[tid + o]; __syncthreads(); }
    if (tid == 0) loss_out[0] = red[0] / 2048.0f;
}

extern "C" void kernel_launch(void* const* d_in, const int* in_sizes, int n_in,
                              void* d_out, int out_size, void* d_ws, size_t ws_size,
                              hipStream_t stream)
{
    const int*   doc  = (const int*)d_in[0];
    const int*   sids = (const int*)d_in[1];
    const float* E    = (const float*)d_in[2];
    const float* WihF = (const float*)d_in[3];
    const float* WhhF = (const float*)d_in[4];
    const float* bihF = (const float*)d_in[5];
    const float* bhhF = (const float*)d_in[6];
    const float* WihB = (const float*)d_in[7];
    const float* WhhB = (const float*)d_in[8];
    const float* bihB = (const float*)d_in[9];
    const float* bhhB = (const float*)d_in[10];
    const float* fcW  = (const float*)d_in[11];
    const float* fcB  = (const float*)d_in[12];
    const float* attW = (const float*)d_in[13];
    const float* attB = (const float*)d_in[14];
    const float* vw   = (const float*)d_in[15];
    const float* dWih = (const float*)d_in[16];
    const float* dbih = (const float*)d_in[17];
    const float* dbhh = (const float*)d_in[18];
    const float* dfcW = (const float*)d_in[19];
    const float* dfcB = (const float*)d_in[20];
    float* out = (float*)d_out;

    char* ws = (char*)d_ws;
    const size_t EMB2 = 0;
    const size_t XG   = EMB2 + 8388608ull;      // emb2: 8192*512*2
    const size_t XGB  = XG   + 33554432ull;     // xg_f: 8192*2048*2
    const size_t HHF  = XGB  + 33554432ull;     // xg_b
    const size_t HHB  = HHF  + 8388608ull;      // h_hist_f
    const size_t HBUF = HHB  + 8388608ull;      // (unused this round)
    const size_t HID  = HBUF + 66560ull;
    // tagged hbuf overlay: first 128KB of EMB2 region (emb2 dead after k_gemm<0>s)
    // overlay (post-scan) inside [XG, XG + 64MB):
    const size_t XATT = XG;
    const size_t ENER = XATT + 25165824ull;
    const size_t ATT  = ENER + 8388608ull;
    const size_t WEI  = ATT  + 32768ull;
    const size_t XDEC = WEI  + 65536ull;
    const size_t GDEC = XDEC + 6291456ull;
    const size_t XPRD = GDEC + 8388608ull;
    const size_t PART = XPRD + 8388608ull;

    u16* emb2  = (u16*)(ws + EMB2);
    u16* xgf   = (u16*)(ws + XG);
    u16* xgb   = (u16*)(ws + XGB);
    u16* hhf   = (u16*)(ws + HHF);
    u16* hhb   = (u16*)(ws + HHB);
    u32* hbuf  = (u32*)(ws + EMB2);             // 4 x 32KB tagged buffers
    u16* hid   = (u16*)(ws + HID);
    u16* xatt  = (u16*)(ws + XATT);
    u16* ener  = (u16*)(ws + ENER);
    float* att = (float*)(ws + ATT);
    float* wei = (float*)(ws + WEI);
    u16* xdec  = (u16*)(ws + XDEC);
    u16* gdec  = (u16*)(ws + GDEC);
    u16* xprd  = (u16*)(ws + XPRD);
    float* part= (float*)(ws + PART);

    (void)in_sizes; (void)n_in; (void)out_size; (void)ws_size;

    k_embed<<<dim3(8192), dim3(64), 0, stream>>>(doc, E, emb2);
    k_gemm<0><<<dim3(16, 64), dim3(256), 0, stream>>>(emb2, WihF, (void*)xgf, bihF, bhhF, 8192, 2048, 512);
    k_gemm<0><<<dim3(16, 64), dim3(256), 0, stream>>>(emb2, WihB, (void*)xgb, bihB, bhhB, 8192, 2048, 512);
    k_init<<<dim3(128), dim3(256), 0, stream>>>(hbuf);
    k_lstm<<<dim3(16), dim3(256), 0, stream>>>(xgf, xgb, WhhF, WhhB, hhf, hhb, hbuf);
    k_fc<<<dim3(32), dim3(256), 0, stream>>>(hhf, hhb, fcW, fcB, hid);
    k_packatt<<<dim3(8192), dim3(256), 0, stream>>>(hid, hhf, hhb, xatt);
    k_gemm<1><<<dim3(4, 64), dim3(256), 0, stream>>>(xatt, attW, (void*)ener, attB, (const float*)0, 8192, 512, 1536);
    k_att<<<dim3(2048), dim3(256), 0, stream>>>(ener, vw, doc, att);
    k_smw<<<dim3(16), dim3(256), 0, stream>>>(att, hhf, hhb, wei);
    k_packdec<<<dim3(2048), dim3(256), 0, stream>>>(sids, E, wei, xdec, xprd);
    k_gemm<0><<<dim3(16, 16), dim3(256), 0, stream>>>(xdec, dWih, (void*)gdec, dbih, dbhh, 2048, 2048, 1536);
    k_gate<<<dim3(4096), dim3(256), 0, stream>>>(gdec, xprd);
    k_gemm<2><<<dim3(166, 16), dim3(256), 0, stream>>>(xprd, dfcW, (void*)out, dfcB, (const float*)0, 2048, 21128, 2048);
    k_lossp<<<dim3(512), dim3(128), 0, stream>>>(out, part);
    k_lossm<<<dim3(1), dim3(256), 0, stream>>>(part, out, sids, out + (size_t)BB * VV * TT);
}

// Round 3
// 4864.376 us; speedup vs baseline: 1.7590x; 1.7590x over previous
//
#include <hip/hip_runtime.h>
#include <math.h>

typedef __attribute__((ext_vector_type(8))) short bf16x8;
typedef __attribute__((ext_vector_type(4))) float f32x4;
typedef unsigned int u32;
typedef unsigned short u16;
typedef unsigned long long u64;

#define BB 16
#define LL 512
#define TT 128
#define VV 21128
#define DD 512

__device__ __forceinline__ float b2f(u16 h){ return __uint_as_float(((u32)h) << 16); }
__device__ __forceinline__ u16 f2bf(float x){
    u32 u = __float_as_uint(x);
    return (u16)((u + 0x7fffu + ((u >> 16) & 1u)) >> 16);
}
__device__ __forceinline__ float sigf(float x){ return 1.0f / (1.0f + __expf(-x)); }
__device__ __forceinline__ bf16x8 pack8(float4 a, float4 b){
    bf16x8 r;
    r[0]=(short)f2bf(a.x); r[1]=(short)f2bf(a.y); r[2]=(short)f2bf(a.z); r[3]=(short)f2bf(a.w);
    r[4]=(short)f2bf(b.x); r[5]=(short)f2bf(b.y); r[6]=(short)f2bf(b.z); r[7]=(short)f2bf(b.w);
    return r;
}

// ---------------- zero scratch ----------------
__global__ void kz(u32* p, int n){
    int i = blockIdx.x * 256 + threadIdx.x;
    if (i < n) p[i] = 0u;
}

// ---------------- embedding: emb2[l*16+b] = bf16(E[doc[b][l]]) ----------------
__global__ void k_embed(const int* __restrict__ doc, const float* __restrict__ E,
                        u16* __restrict__ emb2){
    int r = blockIdx.x;            // l*16 + b
    int lane = threadIdx.x;        // 64
    int l = r >> 4, b = r & 15;
    int tok = doc[b * LL + l];
    const float* src = E + (size_t)tok * DD + lane * 8;
    float4 a = *(const float4*)(src);
    float4 c = *(const float4*)(src + 4);
    *(bf16x8*)(emb2 + (size_t)r * DD + lane * 8) = pack8(a, c);
}

// ---------------- generic 128x128 MFMA GEMM, C = A(bf16) * Bt(f32->bf16)^T ----
// MODE 0: out bf16 = acc + b1[n] + b2[n]     (row-major MxN)
// MODE 1: out bf16 = tanh(acc + b1[n])       (row-major MxN)
// MODE 2: pred epilogue: rows = b*128 + t; out[b,v,t] f32 (B,V,T), t==0 -> 0
template<int MODE>
__global__ __launch_bounds__(256) void k_gemm(
    const u16* __restrict__ A, const float* __restrict__ Bt, void* __restrict__ Out,
    const float* __restrict__ b1, const float* __restrict__ b2, int M, int N, int K)
{
    __shared__ u16 smem[17408];           // 34816 B
    u16* sA = smem;                       // 128 x 56
    u16* sB = smem + 128 * 56;
    int tid = threadIdx.x;
    int nb = blockIdx.x, mb = blockIdx.y;
    int wv = tid >> 6, lane = tid & 63;
    int wm = wv >> 1, wn = wv & 1;
    int lrow = lane & 15, quad = lane >> 4;
    f32x4 acc[4][4] = {};
    int kt_n = K >> 5;
    for (int kt = 0; kt < kt_n; ++kt){
        int k0 = kt << 5;
        bf16x8 va[2];
        u64 qb[4];
        #pragma unroll
        for (int h = 0; h < 2; ++h){
            int c = tid + (h << 8);
            int row = c >> 2, c4 = c & 3;
            va[h] = *(const bf16x8*)(A + (size_t)(mb * 128 + row) * K + k0 + c4 * 8);
        }
        #pragma unroll
        for (int h = 0; h < 4; ++h){
            int c = tid + (h << 8);
            int row = c >> 3, seg = c & 7;
            int rb = nb * 128 + row; rb = rb < N ? rb : N - 1;
            float4 v = *(const float4*)(Bt + (size_t)rb * K + k0 + seg * 4);
            qb[h] = (u64)f2bf(v.x) | ((u64)f2bf(v.y) << 16) |
                    ((u64)f2bf(v.z) << 32) | ((u64)f2bf(v.w) << 48);
        }
        __syncthreads();
        #pragma unroll
        for (int h = 0; h < 2; ++h){
            int c = tid + (h << 8);
            int row = c >> 2, c4 = c & 3;
            *(bf16x8*)(sA + row * 56 + c4 * 8) = va[h];
        }
        #pragma unroll
        for (int h = 0; h < 4; ++h){
            int c = tid + (h << 8);
            int row = c >> 3, seg = c & 7;
            *(u64*)(sB + row * 56 + seg * 4) = qb[h];
        }
        __syncthreads();
        bf16x8 af[4], bfr[4];
        #pragma unroll
        for (int i = 0; i < 4; ++i){
            af[i]  = *(const bf16x8*)(sA + (wm * 64 + i * 16 + lrow) * 56 + quad * 8);
            bfr[i] = *(const bf16x8*)(sB + (wn * 64 + i * 16 + lrow) * 56 + quad * 8);
        }
        #pragma unroll
        for (int i = 0; i < 4; ++i)
            #pragma unroll
            for (int j = 0; j < 4; ++j)
                acc[i][j] = __builtin_amdgcn_mfma_f32_16x16x32_bf16(af[i], bfr[j], acc[i][j], 0, 0, 0);
    }

    if (MODE == 0 || MODE == 1){
        u16* O = (u16*)Out;
        #pragma unroll
        for (int i = 0; i < 4; ++i){
            int rowb = mb * 128 + wm * 64 + i * 16 + quad * 4;
            #pragma unroll
            for (int j = 0; j < 4; ++j){
                int col = nb * 128 + wn * 64 + j * 16 + lrow;
                float bias = b1[col] + (b2 ? b2[col] : 0.0f);
                #pragma unroll
                for (int r = 0; r < 4; ++r){
                    float v = acc[i][j][r] + bias;
                    if (MODE == 1) v = tanhf(v);
                    O[(size_t)(rowb + r) * N + col] = f2bf(v);
                }
            }
        }
    } else {
        // transpose tile through LDS (f32), 2 phases of 64 v-rows
        float* Of = (float*)Out;
        float* lds_f = (float*)smem;          // 64 x 132 f32 = 33792 B
        #pragma unroll
        for (int h = 0; h < 2; ++h){
            __syncthreads();
            if (wn == h){
                #pragma unroll
                for (int j = 0; j < 4; ++j){
                    int nl = j * 16 + lrow;
                    int vg = nb * 128 + h * 64 + nl;
                    float bias = (vg < VV) ? b1[vg] : 0.0f;
                    #pragma unroll
                    for (int i = 0; i < 4; ++i){
                        #pragma unroll
                        for (int r = 0; r < 4; ++r){
                            int tl = wm * 64 + i * 16 + quad * 4 + r;
                            lds_f[nl * 132 + tl] = (tl == 0) ? 0.0f : (acc[i][j][r] + bias);
                        }
                    }
                }
            }
            __syncthreads();
            int vloc = tid >> 2, seg = tid & 3;
            int ng = nb * 128 + h * 64 + vloc;
            if (ng < VV){
                float4* dst = (float4*)(Of + ((size_t)mb * VV + ng) * TT + seg * 32);
                const float4* src = (const float4*)(lds_f + vloc * 132 + seg * 32);
                #pragma unroll
                for (int q = 0; q < 8; ++q) dst[q] = src[q];
            }
        }
    }
}

// ---------------- persistent BiLSTM scan, thin relaxed-flag transport ----------
// 16 blocks x 256 thr. dir = blk>>3; wave slice w = (blk&7)*4 + wv in 0..31,
// dims d0 = w*16. Each wave computes all 4 gates for its 16 dims (no LDS, no
// __syncthreads). Protocol (all traffic reaches the shared LLC, which
// serializes; no fences/invalidates anywhere):
//   producer: relaxed sc1 h-stores -> s_waitcnt vmcnt(0) -> relaxed flag=s+1
//   consumer: busy-poll 32 packed u32 flags (relaxed, 2 lines/iter) until all
//             >= s, then bulk-load h (relaxed). Double-buffer by parity;
//             overrun impossible by flag transitivity.
__global__ __launch_bounds__(256, 1) void k_lstm(
    const u16* __restrict__ xg_f, const u16* __restrict__ xg_b,
    const float* __restrict__ Whh_f, const float* __restrict__ Whh_b,
    u16* __restrict__ hist_f, u16* __restrict__ hist_b,
    u32* __restrict__ hbuf, u32* __restrict__ flags)
{
    int tid = threadIdx.x;
    int wv = tid >> 6, lane = tid & 63;
    int blk = blockIdx.x;
    int dir = blk >> 3;
    int w = ((blk & 7) << 2) + wv;        // 0..31
    int d0 = w << 4;
    int lrow = lane & 15, quad = lane >> 4;

    const u16* xg  = dir ? xg_b : xg_f;
    const float* Whh = dir ? Whh_b : Whh_f;
    u16* hist = dir ? hist_b : hist_f;
    u32* hb_base = hbuf + (dir << 13);            // 2 parity x 4096 u32 (16KB)
    u32* myflag = flags + (dir << 5) + w;
    const u32* pflag = flags + (dir << 5) + (lane & 31);

    // B fragments: Whh rows (gate*512 + d0 + lrow), all K, packed bf16
    bf16x8 bfr[4][16];
    #pragma unroll
    for (int g = 0; g < 4; ++g){
        const float* wp = Whh + (size_t)((g << 9) + d0 + lrow) * DD;
        #pragma unroll
        for (int kb = 0; kb < 16; ++kb){
            float4 x0 = *(const float4*)(wp + kb * 32 + quad * 8);
            float4 x1 = *(const float4*)(wp + kb * 32 + quad * 8 + 4);
            bfr[g][kb] = pack8(x0, x1);
        }
    }
    float c_reg[4] = {0.0f, 0.0f, 0.0f, 0.0f};

    for (int s = 0; s < LL; ++s){
        int t = dir ? (LL - 1 - s) : s;
        u32* hb_r = hb_base + ((s & 1) << 12);
        u32* hb_w = hb_base + (((s + 1) & 1) << 12);

        // prefetch xg (precomputed input gates) — issue before the poll
        u16 xv[4][4];
        const u16* xgp = xg + (size_t)(t << 4) * 2048 + d0 + lrow;
        #pragma unroll
        for (int g = 0; g < 4; ++g)
            #pragma unroll
            for (int r = 0; r < 4; ++r)
                xv[g][r] = xgp[(size_t)((quad << 2) + r) * 2048 + (g << 9)];
        __builtin_amdgcn_sched_barrier(0);

        // thin relaxed busy-poll: 32 flags (4B each, 2 cache lines per wave)
        if (s){
            u32 tgt = (u32)s;
            while (1){
                u32 v = __hip_atomic_load(pflag, __ATOMIC_RELAXED, __HIP_MEMORY_SCOPE_AGENT);
                if (__all((int)(v >= tgt))) break;
            }
        }
        __builtin_amdgcn_sched_barrier(0);

        // bulk-load h_s: lane reads batch=lrow, dims kb*32+quad*8..+7 (packed u32)
        const u64* hrow = (const u64*)(hb_r + (lrow << 8));
        bf16x8 af[16];
        #pragma unroll
        for (int kb = 0; kb < 16; ++kb){
            union { u64 q[2]; bf16x8 v; } u;
            u.q[0] = __hip_atomic_load(hrow + kb * 8 + quad * 2,     __ATOMIC_RELAXED, __HIP_MEMORY_SCOPE_AGENT);
            u.q[1] = __hip_atomic_load(hrow + kb * 8 + quad * 2 + 1, __ATOMIC_RELAXED, __HIP_MEMORY_SCOPE_AGENT);
            af[kb] = u.v;
        }

        f32x4 acc[4] = {};
        #pragma unroll
        for (int kb = 0; kb < 16; ++kb){
            #pragma unroll
            for (int g = 0; g < 4; ++g)
                acc[g] = __builtin_amdgcn_mfma_f32_16x16x32_bf16(af[kb], bfr[g][kb], acc[g], 0, 0, 0);
        }

        // gates: lane holds (dim = d0+lrow, batches quad*4+r); all 4 gates local
        u32 hw[4]; int hb_ok[4];
        #pragma unroll
        for (int r = 0; r < 4; ++r){
            float gi = acc[0][r] + b2f(xv[0][r]);
            float gf = acc[1][r] + b2f(xv[1][r]);
            float gg = acc[2][r] + b2f(xv[2][r]);
            float go = acc[3][r] + b2f(xv[3][r]);
            float cv = sigf(gf) * c_reg[r] + sigf(gi) * tanhf(gg);
            c_reg[r] = cv;
            u32 me = (u32)f2bf(sigf(go) * tanhf(cv));
            u32 ot = __shfl_xor(me, 1);
            u32 uw = me | (ot << 16);
            int batch = (quad << 2) + r;
            hw[r] = uw; hb_ok[r] = batch;
            if (!(lane & 1)){
                __hip_atomic_store(hb_w + (batch << 8) + ((d0 + lrow) >> 1), uw,
                                   __ATOMIC_RELAXED, __HIP_MEMORY_SCOPE_AGENT);
            }
        }
        // drain h stores to the LLC, then publish flag (relaxed, no inv/wb)
        asm volatile("s_waitcnt vmcnt(0)" ::: "memory");
        if (lane == 0)
            __hip_atomic_store(myflag, (u32)(s + 1), __ATOMIC_RELAXED, __HIP_MEMORY_SCOPE_AGENT);
        // hist writes off the critical path (not read until after the kernel)
        #pragma unroll
        for (int r = 0; r < 4; ++r){
            if (!(lane & 1))
                *(u32*)(hist + (size_t)((t << 4) + hb_ok[r]) * DD + d0 + lrow) = hw[r];
        }
    }
}

// ---------------- hidden = tanh([h_f|h_b] @ fc_W^T + fc_b) ----------------
__global__ void k_fc(const u16* __restrict__ hist_f, const u16* __restrict__ hist_b,
                     const float* __restrict__ fcW, const float* __restrict__ fcB,
                     u16* __restrict__ hidden){
    int idx = blockIdx.x * 256 + threadIdx.x;   // 8192
    int b = idx >> 9, n = idx & 511;
    const u16* hf = hist_f + (size_t)(511 * 16 + b) * DD;
    const u16* hb = hist_b + (size_t)b * DD;    // t = 0
    const float* w = fcW + (size_t)n * 1024;
    float sacc = 0.0f;
    for (int k = 0; k < 512; ++k) sacc += b2f(hf[k]) * w[k];
    for (int k = 0; k < 512; ++k) sacc += b2f(hb[k]) * w[512 + k];
    hidden[b * 512 + n] = f2bf(tanhf(sacc + fcB[n]));
}

// ---------------- X_att row = [hidden_b | h_f[b,l] | h_b[b,l]] ----------------
__global__ void k_packatt(const u16* __restrict__ hidden, const u16* __restrict__ hist_f,
                          const u16* __restrict__ hist_b, u16* __restrict__ X){
    int r = blockIdx.x;              // b*512 + l
    int b = r >> 9, l = r & 511;
    u16* xr = X + (size_t)r * 1536;
    const u16* hf = hist_f + (size_t)(l * 16 + b) * DD;
    const u16* hb = hist_b + (size_t)(l * 16 + b) * DD;
    const u16* hd = hidden + b * 512;
    for (int j = threadIdx.x; j < 512; j += 256){
        xr[j] = hd[j];
        xr[512 + j] = hf[j];
        xr[1024 + j] = hb[j];
    }
}

// ---------------- att[b,l] = v_w . energy_row, masked ----------------
__global__ void k_att(const u16* __restrict__ energy, const float* __restrict__ vw,
                      const int* __restrict__ doc, float* __restrict__ att){
    int r = blockIdx.x * 4 + (threadIdx.x >> 6);
    int lane = threadIdx.x & 63;
    bf16x8 e = *(const bf16x8*)(energy + (size_t)r * 512 + lane * 8);
    float4 v0 = *(const float4*)(vw + lane * 8);
    float4 v1 = *(const float4*)(vw + lane * 8 + 4);
    float sacc = b2f((u16)e[0]) * v0.x + b2f((u16)e[1]) * v0.y +
                 b2f((u16)e[2]) * v0.z + b2f((u16)e[3]) * v0.w +
                 b2f((u16)e[4]) * v1.x + b2f((u16)e[5]) * v1.y +
                 b2f((u16)e[6]) * v1.z + b2f((u16)e[7]) * v1.w;
    #pragma unroll
    for (int o = 1; o < 64; o <<= 1) sacc += __shfl_xor(sacc, o);
    if (lane == 0){
        int b = r >> 9, l = r & 511;
        att[r] = (doc[b * 512 + l] != 0) ? sacc : -1e10f;
    }
}

// ---------------- softmax over L + weighted = sum_l a[l]*enc[b,l] ----------------
__global__ __launch_bounds__(256) void k_smw(const float* __restrict__ att,
                                             const u16* __restrict__ hist_f,
                                             const u16* __restrict__ hist_b,
                                             float* __restrict__ weighted){
    __shared__ float sa[512];
    __shared__ float red[256];
    int b = blockIdx.x, tid = threadIdx.x;
    float a0 = att[b * 512 + tid], a1 = att[b * 512 + 256 + tid];
    red[tid] = fmaxf(a0, a1); __syncthreads();
    for (int o = 128; o > 0; o >>= 1){ if (tid < o) red[tid] = fmaxf(red[tid], red[tid + o]); __syncthreads(); }
    float mx = red[0]; __syncthreads();
    float e0 = __expf(a0 - mx), e1 = __expf(a1 - mx);
    red[tid] = e0 + e1; __syncthreads();
    for (int o = 128; o > 0; o >>= 1){ if (tid < o) red[tid] += red[tid + o]; __syncthreads(); }
    float inv = 1.0f / red[0];
    sa[tid] = e0 * inv; sa[256 + tid] = e1 * inv;
    __syncthreads();
    #pragma unroll
    for (int ch = 0; ch < 4; ++ch){
        int e = (ch << 8) + tid;
        const u16* src = (e < 512) ? (hist_f + b * DD + e) : (hist_b + b * DD + (e - 512));
        float acc = 0.0f;
        for (int l = 0; l < 512; ++l) acc += sa[l] * b2f(src[(size_t)l * 16 * DD]);
        weighted[b * 1024 + e] = acc;
    }
}

// ---------------- decoder input packing ----------------
__global__ void k_packdec(const int* __restrict__ sids, const float* __restrict__ E,
                          const float* __restrict__ weighted,
                          u16* __restrict__ X_dec, u16* __restrict__ X_pred){
    int r = blockIdx.x;             // b*128 + t
    int b = r >> 7, t = r & 127;
    u16* xd = X_dec + (size_t)r * 1536;
    u16* xp = X_pred + (size_t)r * 2048;
    const float* er = (t > 0) ? (E + (size_t)sids[b * 128 + t - 1] * DD) : (const float*)0;
    for (int j = threadIdx.x; j < 512; j += 256){
        u16 v = (t > 0) ? f2bf(er[j]) : (u16)0;
        xd[j] = v; xp[1536 + j] = v;
    }
    for (int j = threadIdx.x; j < 1024; j += 256){
        u16 wv = f2bf(weighted[b * 1024 + j]);
        xd[512 + j] = wv; xp[512 + j] = wv;
    }
}

// ---------------- decoder gates (c0=0, f unused) ----------------
__global__ void k_gate(const u16* __restrict__ g, u16* __restrict__ X_pred){
    int idx = blockIdx.x * 256 + threadIdx.x;   // 2048*512
    int r = idx >> 9, d = idx & 511;
    const u16* gr = g + (size_t)r * 2048;
    float gi = b2f(gr[d]), gg = b2f(gr[1024 + d]), go = b2f(gr[1536 + d]);
    float c = sigf(gi) * tanhf(gg);
    X_pred[(size_t)r * 2048 + d] = f2bf(sigf(go) * tanhf(c));
}

// ---------------- loss: online softmax partials over V chunks ----------------
__global__ void k_lossp(const float* __restrict__ out, float* __restrict__ part){
    int b = blockIdx.x >> 5, ch = blockIdx.x & 31;
    int t = threadIdx.x;            // 128
    int v0 = ch * 661, v1 = v0 + 661; if (v1 > VV) v1 = VV;
    const float* col = out + (size_t)b * VV * TT + t;
    float m = -1e30f, sacc = 0.0f;
    for (int v = v0; v < v1; ++v){
        float x = col[(size_t)v * TT];
        float nm = fmaxf(m, x);
        sacc = sacc * __expf(m - nm) + __expf(x - nm);
        m = nm;
    }
    float2* p = (float2*)part;
    p[((b * 32 + ch) << 7) + t] = make_float2(m, sacc);
}

__global__ __launch_bounds__(256) void k_lossm(const float* __restrict__ part,
                                               const float* __restrict__ out,
                                               const int* __restrict__ sids,
                                               float* __restrict__ loss_out){
    __shared__ float red[256];
    int tid = threadIdx.x;
    float local = 0.0f;
    #pragma unroll
    for (int p8 = 0; p8 < 8; ++p8){
        int pair = (p8 << 8) + tid;             // 0..2047
        int b = pair >> 7, t = pair & 127;
        const float2* pp = (const float2*)part + ((size_t)(b * 32) << 7) + t;
        float M = -1e30f;
        for (int c = 0; c < 32; ++c) M = fmaxf(M, pp[c << 7].x);
        float S = 0.0f;
        for (int c = 0; c < 32; ++c){ float2 q = pp[c << 7]; S += q.y * __expf(q.x - M); }
        float logZ = M + __logf(S);
        int tgt = sids[b * 128 + t];
        float x = out[(size_t)b * VV * TT + (size_t)tgt * TT + t];
        local += (logZ - x);
    }
    red[tid] = local; __syncthreads();
    for (int o = 128; o > 0; o >>= 1){ if (tid < o) red[tid] += red[tid + o]; __syncthreads(); }
    if (tid == 0) loss_out[0] = red[0] / 2048.0f;
}

extern "C" void kernel_launch(void* const* d_in, const int* in_sizes, int n_in,
                              void* d_out, int out_size, void* d_ws, size_t ws_size,
                              hipStream_t stream)
{
    const int*   doc  = (const int*)d_in[0];
    const int*   sids = (const int*)d_in[1];
    const float* E    = (const float*)d_in[2];
    const float* WihF = (const float*)d_in[3];
    const float* WhhF = (const float*)d_in[4];
    const float* bihF = (const float*)d_in[5];
    const float* bhhF = (const float*)d_in[6];
    const float* WihB = (const float*)d_in[7];
    const float* WhhB = (const float*)d_in[8];
    const float* bihB = (const float*)d_in[9];
    const float* bhhB = (const float*)d_in[10];
    const float* fcW  = (const float*)d_in[11];
    const float* fcB  = (const float*)d_in[12];
    const float* attW = (const float*)d_in[13];
    const float* attB = (const float*)d_in[14];
    const float* vw   = (const float*)d_in[15];
    const float* dWih = (const float*)d_in[16];
    const float* dbih = (const float*)d_in[17];
    const float* dbhh = (const float*)d_in[18];
    const float* dfcW = (const float*)d_in[19];
    const float* dfcB = (const float*)d_in[20];
    float* out = (float*)d_out;

    char* ws = (char*)d_ws;
    const size_t EMB2 = 0;
    const size_t XG   = EMB2 + 8388608ull;      // emb2: 8192*512*2
    const size_t XGB  = XG   + 33554432ull;     // xg_f: 8192*2048*2
    const size_t HHF  = XGB  + 33554432ull;     // xg_b
    const size_t HHB  = HHF  + 8388608ull;      // h_hist_f
    const size_t HBUF = HHB  + 8388608ull;      // (unused this round)
    const size_t HID  = HBUF + 66560ull;
    // hbuf+flags overlay: first 68KB of EMB2 region (emb2 dead after k_gemm<0>s)
    // overlay (post-scan) inside [XG, XG + 64MB):
    const size_t XATT = XG;
    const size_t ENER = XATT + 25165824ull;
    const size_t ATT  = ENER + 8388608ull;
    const size_t WEI  = ATT  + 32768ull;
    const size_t XDEC = WEI  + 65536ull;
    const size_t GDEC = XDEC + 6291456ull;
    const size_t XPRD = GDEC + 8388608ull;
    const size_t PART = XPRD + 8388608ull;

    u16* emb2  = (u16*)(ws + EMB2);
    u16* xgf   = (u16*)(ws + XG);
    u16* xgb   = (u16*)(ws + XGB);
    u16* hhf   = (u16*)(ws + HHF);
    u16* hhb   = (u16*)(ws + HHB);
    u32* hbuf  = (u32*)(ws + EMB2);             // 2dir x 2par x 16KB
    u32* flags = hbuf + 16384;                  // 64 x u32
    u16* hid   = (u16*)(ws + HID);
    u16* xatt  = (u16*)(ws + XATT);
    u16* ener  = (u16*)(ws + ENER);
    float* att = (float*)(ws + ATT);
    float* wei = (float*)(ws + WEI);
    u16* xdec  = (u16*)(ws + XDEC);
    u16* gdec  = (u16*)(ws + GDEC);
    u16* xprd  = (u16*)(ws + XPRD);
    float* part= (float*)(ws + PART);

    (void)in_sizes; (void)n_in; (void)out_size; (void)ws_size;

    k_embed<<<dim3(8192), dim3(64), 0, stream>>>(doc, E, emb2);
    k_gemm<0><<<dim3(16, 64), dim3(256), 0, stream>>>(emb2, WihF, (void*)xgf, bihF, bhhF, 8192, 2048, 512);
    k_gemm<0><<<dim3(16, 64), dim3(256), 0, stream>>>(emb2, WihB, (void*)xgb, bihB, bhhB, 8192, 2048, 512);
    kz<<<dim3(65), dim3(256), 0, stream>>>(hbuf, 16448);
    k_lstm<<<dim3(16), dim3(256), 0, stream>>>(xgf, xgb, WhhF, WhhB, hhf, hhb, hbuf, flags);
    k_fc<<<dim3(32), dim3(256), 0, stream>>>(hhf, hhb, fcW, fcB, hid);
    k_packatt<<<dim3(8192), dim3(256), 0, stream>>>(hid, hhf, hhb, xatt);
    k_gemm<1><<<dim3(4, 64), dim3(256), 0, stream>>>(xatt, attW, (void*)ener, attB, (const float*)0, 8192, 512, 1536);
    k_att<<<dim3(2048), dim3(256), 0, stream>>>(ener, vw, doc, att);
    k_smw<<<dim3(16), dim3(256), 0, stream>>>(att, hhf, hhb, wei);
    k_packdec<<<dim3(2048), dim3(256), 0, stream>>>(sids, E, wei, xdec, xprd);
    k_gemm<0><<<dim3(16, 16), dim3(256), 0, stream>>>(xdec, dWih, (void*)gdec, dbih, dbhh, 2048, 2048, 1536);
    k_gate<<<dim3(4096), dim3(256), 0, stream>>>(gdec, xprd);
    k_gemm<2><<<dim3(166, 16), dim3(256), 0, stream>>>(xprd, dfcW, (void*)out, dfcB, (const float*)0, 2048, 21128, 2048);
    k_lossp<<<dim3(512), dim3(128), 0, stream>>>(out, part);
    k_lossm<<<dim3(1), dim3(256), 0, stream>>>(part, out, sids, out + (size_t)BB * VV * TT);
}